// Round 1
// baseline (263.715 us; speedup 1.0000x reference)
//
#include <hip/hip_runtime.h>

#define D_FEAT 32

// Scatter-add: one thread per (edge, feature) pair.
// 32 consecutive threads handle one edge -> coalesced reads of x[col[e]][0..31]
// and same-cache-line atomics into out[row[e]][0..31].
__global__ void scatter_add_kernel(const float* __restrict__ x,
                                   const int* __restrict__ row,
                                   const int* __restrict__ col,
                                   float* __restrict__ out,
                                   float* __restrict__ deg,
                                   long long total) {
    long long tid = (long long)blockIdx.x * blockDim.x + threadIdx.x;
    if (tid >= total) return;
    int e = (int)(tid >> 5);
    int d = (int)(tid & 31);
    int r = row[e];
    int c = col[e];
    atomicAdd(&out[(long long)r * D_FEAT + d], x[(long long)c * D_FEAT + d]);
    if (d == 0) atomicAdd(&deg[r], 1.0f);
}

// out[i*32+d] /= max(deg[i], 1)
__global__ void finalize_kernel(float* __restrict__ out,
                                const float* __restrict__ deg,
                                int n_out) {
    int tid = blockIdx.x * blockDim.x + threadIdx.x;
    if (tid >= n_out) return;
    float dg = deg[tid >> 5];
    out[tid] = out[tid] / fmaxf(dg, 1.0f);
}

extern "C" void kernel_launch(void* const* d_in, const int* in_sizes, int n_in,
                              void* d_out, int out_size, void* d_ws, size_t ws_size,
                              hipStream_t stream) {
    const float* x = (const float*)d_in[0];
    const int* edge_index = (const int*)d_in[1];

    int n_edges = in_sizes[1] / 2;
    const int* row = edge_index;            // edge_index[0]
    const int* col = edge_index + n_edges;  // edge_index[1]

    int n_nodes = in_sizes[0] / D_FEAT;

    float* out = (float*)d_out;
    float* deg = (float*)d_ws;  // n_nodes floats of scratch

    // Harness poisons d_out/d_ws once and never re-poisons: zero them each call.
    hipMemsetAsync(d_out, 0, (size_t)out_size * sizeof(float), stream);
    hipMemsetAsync(d_ws, 0, (size_t)n_nodes * sizeof(float), stream);

    long long total = (long long)n_edges * D_FEAT;
    int block = 256;
    long long grid = (total + block - 1) / block;
    scatter_add_kernel<<<(int)grid, block, 0, stream>>>(x, row, col, out, deg, total);

    int fin_grid = (out_size + block - 1) / block;
    finalize_kernel<<<fin_grid, block, 0, stream>>>(out, deg, out_size);
}

// Round 2
// 202.750 us; speedup vs baseline: 1.3007x; 1.3007x over previous
//
#include <hip/hip_runtime.h>

#define D_FEAT 32

// ---------------- CSR-build path (no float atomics) ----------------

__global__ void hist_kernel(const int* __restrict__ row, int* __restrict__ cnt, int E) {
    int e = blockIdx.x * blockDim.x + threadIdx.x;
    if (e < E) atomicAdd(&cnt[row[e]], 1);
}

// Phase 1 of exclusive scan: each block of 256 threads scans 1024 elements.
__global__ void scan1_kernel(const int* __restrict__ cnt, int* __restrict__ offs,
                             int* __restrict__ bsum, int N) {
    __shared__ int sh[256];
    int t = threadIdx.x;
    int base = blockIdx.x * 1024 + t * 4;
    int v0 = 0, v1 = 0, v2 = 0, v3 = 0;
    if (base + 0 < N) v0 = cnt[base + 0];
    if (base + 1 < N) v1 = cnt[base + 1];
    if (base + 2 < N) v2 = cnt[base + 2];
    if (base + 3 < N) v3 = cnt[base + 3];
    int s = v0 + v1 + v2 + v3;
    sh[t] = s;
    __syncthreads();
    // Hillis-Steele inclusive scan over 256 partial sums
    for (int off = 1; off < 256; off <<= 1) {
        int val = 0;
        if (t >= off) val = sh[t - off];
        __syncthreads();
        if (t >= off) sh[t] += val;
        __syncthreads();
    }
    int excl = sh[t] - s;  // exclusive prefix of this thread's chunk
    if (t == 255) bsum[blockIdx.x] = sh[255];
    int p = excl;
    if (base + 0 < N) offs[base + 0] = p; p += v0;
    if (base + 1 < N) offs[base + 1] = p; p += v1;
    if (base + 2 < N) offs[base + 2] = p; p += v2;
    if (base + 3 < N) offs[base + 3] = p; p += v3;
}

// Phase 2: serial exclusive scan of the ~98 block sums (single thread; trivial).
__global__ void scan2_kernel(int* __restrict__ bsum, int nb) {
    if (blockIdx.x == 0 && threadIdx.x == 0) {
        int acc = 0;
        for (int i = 0; i < nb; ++i) { int v = bsum[i]; bsum[i] = acc; acc += v; }
    }
}

// Phase 3: add scanned block sums back.
__global__ void scan3_kernel(int* __restrict__ offs, const int* __restrict__ bsum, int N) {
    int i = blockIdx.x * blockDim.x + threadIdx.x;
    if (i < N) offs[i] += bsum[i >> 10];
}

// Scatter col indices into row-sorted order.
__global__ void scatter_kernel(const int* __restrict__ row, const int* __restrict__ col,
                               const int* __restrict__ offs, int* __restrict__ fill,
                               int* __restrict__ scol, int E) {
    int e = blockIdx.x * blockDim.x + threadIdx.x;
    if (e < E) {
        int r = row[e];
        int p = offs[r] + atomicAdd(&fill[r], 1);
        scol[p] = col[e];
    }
}

// Segmented mean: 8 threads per node, one float4 (4 features) each.
__global__ void reduce_kernel(const float* __restrict__ x, const int* __restrict__ scol,
                              const int* __restrict__ offs, const int* __restrict__ cnt,
                              float* __restrict__ out, int N) {
    int tid = blockIdx.x * blockDim.x + threadIdx.x;
    if (tid >= N * 8) return;
    int i = tid >> 3;
    int q = tid & 7;
    int s = offs[i];
    int d = cnt[i];
    const float4* x4 = (const float4*)x;
    float4 acc = make_float4(0.f, 0.f, 0.f, 0.f);
    for (int e = s; e < s + d; ++e) {
        int c = scol[e];
        float4 v = x4[c * 8 + q];
        acc.x += v.x; acc.y += v.y; acc.z += v.z; acc.w += v.w;
    }
    float inv = 1.0f / (float)max(d, 1);
    acc.x *= inv; acc.y *= inv; acc.z *= inv; acc.w *= inv;
    ((float4*)out)[tid] = acc;
}

// ---------------- Fallback atomic path (round-1 kernel) ----------------

__global__ void scatter_add_kernel(const float* __restrict__ x,
                                   const int* __restrict__ row,
                                   const int* __restrict__ col,
                                   float* __restrict__ out,
                                   float* __restrict__ deg,
                                   long long total) {
    long long tid = (long long)blockIdx.x * blockDim.x + threadIdx.x;
    if (tid >= total) return;
    int e = (int)(tid >> 5);
    int d = (int)(tid & 31);
    int r = row[e];
    int c = col[e];
    atomicAdd(&out[(long long)r * D_FEAT + d], x[(long long)c * D_FEAT + d]);
    if (d == 0) atomicAdd(&deg[r], 1.0f);
}

__global__ void finalize_kernel(float* __restrict__ out,
                                const float* __restrict__ deg,
                                int n_out) {
    int tid = blockIdx.x * blockDim.x + threadIdx.x;
    if (tid >= n_out) return;
    float dg = deg[tid >> 5];
    out[tid] = out[tid] / fmaxf(dg, 1.0f);
}

// ---------------- launch ----------------

extern "C" void kernel_launch(void* const* d_in, const int* in_sizes, int n_in,
                              void* d_out, int out_size, void* d_ws, size_t ws_size,
                              hipStream_t stream) {
    const float* x = (const float*)d_in[0];
    const int* edge_index = (const int*)d_in[1];

    int E = in_sizes[1] / 2;
    const int* row = edge_index;      // edge_index[0]
    const int* col = edge_index + E;  // edge_index[1]
    int N = in_sizes[0] / D_FEAT;

    float* out = (float*)d_out;

    int nb = (N + 1023) / 1024;  // scan blocks

    // ws layout (ints): cnt[N] | offs[N] | fill[N] | bsum[nb] | scol[E]
    size_t need = ((size_t)3 * N + nb + E) * sizeof(int);

    if (ws_size >= need) {
        int* cnt  = (int*)d_ws;
        int* offs = cnt + N;
        int* fill = offs + N;
        int* bsum = fill + N;
        int* scol = bsum + nb;

        // zero the counters each call (harness does not re-poison)
        hipMemsetAsync(cnt, 0, (size_t)N * sizeof(int), stream);
        hipMemsetAsync(fill, 0, (size_t)N * sizeof(int), stream);

        int block = 256;
        hist_kernel<<<(E + block - 1) / block, block, 0, stream>>>(row, cnt, E);
        scan1_kernel<<<nb, 256, 0, stream>>>(cnt, offs, bsum, N);
        scan2_kernel<<<1, 64, 0, stream>>>(bsum, nb);
        scan3_kernel<<<(N + block - 1) / block, block, 0, stream>>>(offs, bsum, N);
        scatter_kernel<<<(E + block - 1) / block, block, 0, stream>>>(row, col, offs, fill, scol, E);

        int rthreads = N * 8;
        reduce_kernel<<<(rthreads + block - 1) / block, block, 0, stream>>>(x, scol, offs, cnt, out, N);
    } else {
        // fallback: atomic scatter-add
        float* deg = (float*)d_ws;
        hipMemsetAsync(d_out, 0, (size_t)out_size * sizeof(float), stream);
        hipMemsetAsync(d_ws, 0, (size_t)N * sizeof(float), stream);

        long long total = (long long)E * D_FEAT;
        int block = 256;
        long long grid = (total + block - 1) / block;
        scatter_add_kernel<<<(int)grid, block, 0, stream>>>(x, row, col, out, deg, total);
        finalize_kernel<<<(out_size + 255) / 256, 256, 0, stream>>>(out, deg, out_size);
    }
}